// Round 3
// baseline (320.589 us; speedup 1.0000x reference)
//
#include <hip/hip_runtime.h>
#include <stdint.h>
#include <float.h>

typedef _Float16 f16x8 __attribute__((ext_vector_type(8)));  // 8 f16 (4 VGPRs)
typedef _Float16 f16x4 __attribute__((ext_vector_type(4)));
typedef float f32x4 __attribute__((ext_vector_type(4)));

#define D_DIM 256
#define K_CODES 8192
#define M_TOK 32768
#define MARGIN 0.05f

__device__ __forceinline__ void gload_lds16(const void* g, void* l) {
  __builtin_amdgcn_global_load_lds(
      (__attribute__((address_space(1))) void*)(uintptr_t)g,
      (__attribute__((address_space(3))) void*)l,
      16, 0, 0);
}

// ---------------------------------------------------------------------------
// Kernel 1: codebook fp32 -> f16 (RNE) + fp32 row norms.
// grid 2048 x 256: one wave per code row (64 lanes x 4 floats).
// ---------------------------------------------------------------------------
__global__ __launch_bounds__(256) void split_cb(
    const float* __restrict__ cb, _Float16* __restrict__ c_h,
    float* __restrict__ c_norm) {
  const int w = threadIdx.x >> 6, l = threadIdx.x & 63;
  const int code = blockIdx.x * 4 + w;
  const int base = code * D_DIM + l * 4;
  f32x4 v = *(const f32x4*)(cb + base);
  f16x4 hv;
  float ns = 0.f;
#pragma unroll
  for (int j = 0; j < 4; ++j) {
    float f = v[j];
    ns = fmaf(f, f, ns);
    hv[j] = (_Float16)f;  // RNE
  }
  *(f16x4*)(c_h + base) = hv;
#pragma unroll
  for (int m = 32; m > 0; m >>= 1) ns += __shfl_xor(ns, m);
  if (l == 0) c_norm[code] = ns;
}

// ---------------------------------------------------------------------------
// Kernel 2: MFMA distance + per-token top-2 (score,index).
// Grid 256 = 128 row-groups x 2 code-sets (1 block/CU, single round).
// Block: 512 thr (8 waves); wave owns 32 rows (2 row-frags, x_h+x_l f16 in
// regs); sweeps 4096 codes in 64 tiles of 64. LDS: dbuf [64 codes][256] f16
// = 2 x 32 KB, XOR-swizzled ((row&7)<<4) via pre-swizzled global source
// (linear global_load_lds dest, rule #21).
// Score = c_norm[n] - 2*(x_h + x_l).c_h   (x_norm dropped: row-constant)
// ---------------------------------------------------------------------------
__global__ __launch_bounds__(512, 2) void vq_main(
    const float* __restrict__ x, const _Float16* __restrict__ c_h,
    const float* __restrict__ c_norm,
    float* __restrict__ out_s1, float* __restrict__ out_s2,
    int* __restrict__ out_i1, int* __restrict__ out_i2) {
  __shared__ char smem[65536];
  const int t = threadIdx.x;
  const int w = t >> 6, l = t & 63;
  const int lrow = l & 15, lg = l >> 4;
  const int cs = blockIdx.x & 1;        // code-set
  const int rg = blockIdx.x >> 1;       // row-group
  const int row0 = rg * 256 + w * 32;   // wave's 32 rows
  const int code0 = cs * 4096;
  const char* chb = (const char*)c_h;

  // A fragments: 32 rows x 256 k, f16 hi+lo, in registers (128 VGPR).
  // mfma 16x16x32 A layout: lane holds row = l&15, k = (l>>4)*8 + j.
  f16x8 a_hi[2][8], a_lo[2][8];
#pragma unroll
  for (int rb = 0; rb < 2; ++rb) {
    const float* xr = x + (size_t)(row0 + rb * 16 + lrow) * D_DIM;
#pragma unroll
    for (int kk = 0; kk < 8; ++kk) {
      f32x4 p0 = *(const f32x4*)(xr + kk * 32 + lg * 8);
      f32x4 p1 = *(const f32x4*)(xr + kk * 32 + lg * 8 + 4);
      float v[8];
#pragma unroll
      for (int j = 0; j < 4; ++j) { v[j] = p0[j]; v[j + 4] = p1[j]; }
#pragma unroll
      for (int j = 0; j < 8; ++j) {
        _Float16 h = (_Float16)v[j];          // RNE
        a_hi[rb][kk][j] = h;
        a_lo[rb][kk][j] = (_Float16)(v[j] - (float)h);
      }
    }
  }

  float bs1[2][4], bs2[2][4];
  int bi1[2][4], bi2[2][4];
#pragma unroll
  for (int rb = 0; rb < 2; ++rb)
#pragma unroll
    for (int j = 0; j < 4; ++j) {
      bs1[rb][j] = FLT_MAX; bs2[rb][j] = FLT_MAX;
      bi1[rb][j] = 0; bi2[rb][j] = 0;
    }
  const int swzr = (l & 7) << 4;

  // stage one 64-code f16 tile (32 KB): LDS dest linear, source pre-swizzled.
  auto stage = [&](char* bufb, int n0) {
#pragma unroll
    for (int i = 0; i < 4; ++i) {
      const int s = (i * 512 + t) * 16;   // byte slot in 32 KB tile
      const int row = s >> 9;             // code row-in-tile 0..63
      const int off = s & 511;
      const int srco = (n0 + row) * 512 + (off ^ ((row & 7) << 4));
      char* dst = bufb + i * 8192 + w * 1024;  // wave-uniform base
      gload_lds16(chb + srco, dst);
    }
  };

  stage(smem, code0);
  __syncthreads();

  for (int it = 0; it < 64; ++it) {
    const int n0 = code0 + it * 64;
    char* cur = smem + (it & 1) * 32768;
    if (it + 1 < 64) stage(smem + ((it + 1) & 1) * 32768, n0 + 64);

    float cn[4];
#pragma unroll
    for (int ct = 0; ct < 4; ++ct) cn[ct] = c_norm[n0 + ct * 16 + lrow];

    f32x4 acc[2][4];
#pragma unroll
    for (int rb = 0; rb < 2; ++rb)
#pragma unroll
      for (int ct = 0; ct < 4; ++ct) { f32x4 z = {0.f, 0.f, 0.f, 0.f}; acc[rb][ct] = z; }

#pragma unroll
    for (int kk = 0; kk < 8; ++kk) {
      const int coff = (kk * 64 + lg * 16) ^ swzr;  // swizzled read offset
      f16x8 bh[4];
#pragma unroll
      for (int ct = 0; ct < 4; ++ct)
        bh[ct] = *(const f16x8*)(cur + (ct * 16 + lrow) * 512 + coff);
      // 16 MFMAs; dependents on the same acc are 8 apart
#pragma unroll
      for (int ct = 0; ct < 4; ++ct)
#pragma unroll
        for (int rb = 0; rb < 2; ++rb)
          acc[rb][ct] = __builtin_amdgcn_mfma_f32_16x16x32_f16(a_hi[rb][kk], bh[ct], acc[rb][ct], 0, 0, 0);
#pragma unroll
      for (int ct = 0; ct < 4; ++ct)
#pragma unroll
        for (int rb = 0; rb < 2; ++rb)
          acc[rb][ct] = __builtin_amdgcn_mfma_f32_16x16x32_f16(a_lo[rb][kk], bh[ct], acc[rb][ct], 0, 0, 0);
    }

    // top-2 update. C/D layout: col = l&15 (code), row = (l>>4)*4 + j (token).
    // n ascends per lane (ct, it ascending) -> strict '<' keeps lowest index.
#pragma unroll
    for (int ct = 0; ct < 4; ++ct) {
      const int n = n0 + ct * 16 + lrow;
#pragma unroll
      for (int rb = 0; rb < 2; ++rb)
#pragma unroll
        for (int j = 0; j < 4; ++j) {
          float s = fmaf(-2.f, acc[rb][ct][j], cn[ct]);
          bool lt1 = s < bs1[rb][j];
          bool lt2 = s < bs2[rb][j];
          bs2[rb][j] = lt1 ? bs1[rb][j] : (lt2 ? s : bs2[rb][j]);
          bi2[rb][j] = lt1 ? bi1[rb][j] : (lt2 ? n : bi2[rb][j]);
          bs1[rb][j] = lt1 ? s : bs1[rb][j];
          bi1[rb][j] = lt1 ? n : bi1[rb][j];
        }
    }
    __syncthreads();  // buf reuse fence; drains this iter's prefetch (vmcnt)
  }

  // merge top-2 sets across the 16 lanes (lrow bits) sharing each token
#pragma unroll
  for (int m = 8; m >= 1; m >>= 1) {
#pragma unroll
    for (int rb = 0; rb < 2; ++rb)
#pragma unroll
      for (int j = 0; j < 4; ++j) {
        float u1 = __shfl_xor(bs1[rb][j], m);
        float u2 = __shfl_xor(bs2[rb][j], m);
        int v1 = __shfl_xor(bi1[rb][j], m);
        int v2 = __shfl_xor(bi2[rb][j], m);
        bool take = (u1 < bs1[rb][j]) || (u1 == bs1[rb][j] && v1 < bi1[rb][j]);
        if (take) {
          bool oldFirst = (bs1[rb][j] < u2) || (bs1[rb][j] == u2 && bi1[rb][j] < v2);
          bs2[rb][j] = oldFirst ? bs1[rb][j] : u2;
          bi2[rb][j] = oldFirst ? bi1[rb][j] : v2;
          bs1[rb][j] = u1; bi1[rb][j] = v1;
        } else {
          bool rep = (u1 < bs2[rb][j]) || (u1 == bs2[rb][j] && v1 < bi2[rb][j]);
          bs2[rb][j] = rep ? u1 : bs2[rb][j];
          bi2[rb][j] = rep ? v1 : bi2[rb][j];
        }
      }
  }
  if (lrow == 0) {
#pragma unroll
    for (int rb = 0; rb < 2; ++rb)
#pragma unroll
      for (int j = 0; j < 4; ++j) {
        const int tok = row0 + rb * 16 + lg * 4 + j;
        const int o = cs * M_TOK + tok;
        out_s1[o] = bs1[rb][j];
        out_s2[o] = bs2[rb][j];
        out_i1[o] = bi1[rb][j];
        out_i2[o] = bi2[rb][j];
      }
  }
}

// ---------------------------------------------------------------------------
// Kernel 3: merge the 2 code-set candidates; fp64 rescore top-2 if margin
// small (protects argmin against f16 quantization noise on near-ties).
// ---------------------------------------------------------------------------
__global__ __launch_bounds__(256) void vq_merge(
    const float* __restrict__ s1a, const float* __restrict__ s2a,
    const int* __restrict__ i1a, const int* __restrict__ i2a,
    const float* __restrict__ x, const float* __restrict__ cb,
    int* __restrict__ fidx) {
  const int tk = blockIdx.x * 256 + threadIdx.x;
  float b1 = FLT_MAX, b2 = FLT_MAX;
  int j1 = 0, j2 = 0;
#pragma unroll
  for (int cs = 0; cs < 2; ++cs) {
    const int o = cs * M_TOK + tk;
    float u1 = s1a[o], u2 = s2a[o];
    int v1 = i1a[o], v2 = i2a[o];
    bool take = (u1 < b1) || (u1 == b1 && v1 < j1);
    if (take) {
      bool oldFirst = (b1 < u2) || (b1 == u2 && j1 < v2);
      b2 = oldFirst ? b1 : u2;
      j2 = oldFirst ? j1 : v2;
      b1 = u1; j1 = v1;
    } else {
      bool rep = (u1 < b2) || (u1 == b2 && v1 < j2);
      b2 = rep ? u1 : b2;
      j2 = rep ? v1 : j2;
    }
  }
  int pick = j1;
  if (b2 - b1 < MARGIN) {
    const float* xr = x + (size_t)tk * D_DIM;
    const float* c1 = cb + (size_t)j1 * D_DIM;
    const float* c2 = cb + (size_t)j2 * D_DIM;
    double d1 = 0.0, d2 = 0.0;
    for (int d = 0; d < D_DIM; ++d) {
      double xv = (double)xr[d];
      double e1 = xv - (double)c1[d];
      double e2 = xv - (double)c2[d];
      d1 = fma(e1, e1, d1);
      d2 = fma(e2, e2, d2);
    }
    if (d2 < d1 || (d2 == d1 && j2 < j1)) pick = j2;
  }
  fidx[tk] = pick;
}

// ---------------------------------------------------------------------------
// Kernel 4: gather codebook rows (bitwise fp32 codebook values).
// ---------------------------------------------------------------------------
__global__ __launch_bounds__(256) void vq_gather(
    const int* __restrict__ idx, const float* __restrict__ cb,
    float* __restrict__ out) {
  const int w = threadIdx.x >> 6, l = threadIdx.x & 63;
  const int tk = blockIdx.x * 4 + w;
  const int id = idx[tk];
  f32x4 v = *(const f32x4*)(cb + (size_t)id * D_DIM + l * 4);
  *(f32x4*)(out + (size_t)tk * D_DIM + l * 4) = v;
}

extern "C" void kernel_launch(void* const* d_in, const int* in_sizes, int n_in,
                              void* d_out, int out_size, void* d_ws, size_t ws_size,
                              hipStream_t stream) {
  const float* x = (const float*)d_in[0];    // [8,4096,256] fp32
  const float* cbk = (const float*)d_in[1];  // [8192,256] fp32
  float* out = (float*)d_out;                // [8,4096,256] fp32
  char* ws = (char*)d_ws;
  // ws: c_h 4M | c_norm 32K (pad 64K) | s1 256K | s2 256K | i1 256K |
  //     i2 256K | fidx 128K   (total ~5.3 MB)
  _Float16* c_h = (_Float16*)(ws);
  float* c_norm = (float*)(ws + (4u << 20));
  char* cand = ws + (4u << 20) + (64u << 10);
  float* s1 = (float*)(cand);
  float* s2 = (float*)(cand + (256u << 10));
  int* i1 = (int*)(cand + (512u << 10));
  int* i2 = (int*)(cand + (768u << 10));
  int* fidx = (int*)(cand + (1024u << 10));

  split_cb<<<K_CODES / 4, 256, 0, stream>>>(cbk, c_h, c_norm);
  vq_main<<<256, 512, 0, stream>>>(x, c_h, c_norm, s1, s2, i1, i2);
  vq_merge<<<M_TOK / 256, 256, 0, stream>>>(s1, s2, i1, i2, x, cbk, fidx);
  vq_gather<<<M_TOK / 4, 256, 0, stream>>>(fidx, cbk, out);
}